// Round 17
// baseline (420.079 us; speedup 1.0000x reference)
//
#include <hip/hip_runtime.h>
#include <hip/hip_fp16.h>

#define NN 100000
#define EE 1600000
#define HH 64
#define GG 64
#define NBK 391    // buckets of 256 nodes: dst>>8
#define CAP 8192   // fixed bucket capacity (mean load 4092, max ~4400)

typedef _Float16 f16x8 __attribute__((ext_vector_type(8)));
typedef _Float16 f16x4 __attribute__((ext_vector_type(4)));
typedef float f32x4 __attribute__((ext_vector_type(4)));

// ---------------- workspace layout (bytes) ----------------
// rowStart : int[NN]           @ 0
// rowLen   : int[NN]           @ 400000
// dinv     : float[NN]         @ 800000
// srcs     : int[NBK*CAP]      @ 1200000   (ends 14012288)
// u (fp32) : float[8][NN][8]   @ 14012288  (8 eighth-tables, 3.2MB each; ends 39612288)
// hb(fp16) : half[NN*64]       @ 39612288  (ends 52412288)
// tmp      : int[NBK*CAP]      @ 39612288  (overlaps hb; dead after bsort, hb written after)
// Wh       : half[3][16384]    @ 52424576  (32KB/layer, ends 52522880)
// gsum     : float[4096]       @ 52522880
// gcnt     : float[64]         @ 52539264
// bcur     : int[NBK]          @ 52539520  (ends 52541084)
//
// Failed-experiment ledger (keep!): R13 producer-local gemm: no FETCH change
// (L2 invalidated at dispatch boundary). R14/15 warm_slice + nt hints: agg
// 46->69us, FETCH 31->41MB. R16 agg structure (fp16 quarters) = 46us/31MB,
// VALUBusy 43% -> VALU-bound on cvt+add; R17 = fp32 eighth-tables, pk_add path.

static inline int cdiv_h(int a, int b) { return (a + b - 1) / b; }

// ---- partition edges into fixed-capacity buckets (391 blocks x 4096 edges) ----
__global__ __launch_bounds__(256) void bplace_kernel(const int* __restrict__ ei,
                                                     int* __restrict__ bcur,
                                                     int* __restrict__ tmp) {
    __shared__ int h[NBK];
    __shared__ int boff[NBK];
    for (int t = threadIdx.x; t < NBK; t += 256) h[t] = 0;
    __syncthreads();
    int base = blockIdx.x * 4096;
#pragma unroll 4
    for (int i = 0; i < 16; i++) {
        int e = base + i * 256 + threadIdx.x;
        if (e < EE) atomicAdd(&h[ei[EE + e] >> 8], 1);
    }
    __syncthreads();
    for (int t = threadIdx.x; t < NBK; t += 256) {
        int c = h[t];
        boff[t] = c ? (t * CAP + atomicAdd(&bcur[t], c)) : 0;
        h[t] = 0;  // reuse as running cursor
    }
    __syncthreads();
#pragma unroll 4
    for (int i = 0; i < 16; i++) {
        int e = base + i * 256 + threadIdx.x;
        if (e < EE) {
            int s0 = ei[e];
            int d = ei[EE + e];
            int b = d >> 8;
            int p = boff[b] + atomicAdd(&h[b], 1);
            tmp[p] = (s0 << 8) | (d & 255);
        }
    }
}

// ---- per-bucket counting sort: srcs (bucket-strided CSR), rowStart/Len, dinv ----
__global__ __launch_bounds__(256) void bsort_kernel(const int* __restrict__ tmp,
                                                    const int* __restrict__ bcur,
                                                    int* __restrict__ rowStart,
                                                    int* __restrict__ rowLen,
                                                    float* __restrict__ dinv,
                                                    int* __restrict__ srcs) {
    int b = blockIdx.x;
    int n0 = b << 8;
    int e0 = b * CAP;
    int e1 = e0 + bcur[b];
    int t = threadIdx.x;
    __shared__ int cnt[256];
    __shared__ int st[256];
    cnt[t] = 0;
    __syncthreads();
    for (int e = e0 + t; e < e1; e += 256) atomicAdd(&cnt[tmp[e] & 255], 1);
    __syncthreads();
    int v = cnt[t];
    st[t] = v;
    __syncthreads();
    for (int off = 1; off < 256; off <<= 1) {
        int w = (t >= off) ? st[t - off] : 0;
        __syncthreads();
        st[t] += w;
        __syncthreads();
    }
    int excl = st[t] - v;
    int n = n0 + t;
    if (n < NN) {
        rowStart[n] = e0 + excl;
        rowLen[n] = v;
        dinv[n] = rsqrtf((float)v + 1.0f);
    }
    __syncthreads();
    cnt[t] = e0 + excl;  // absolute cursor
    __syncthreads();
    for (int e = e0 + t; e < e1; e += 256) {
        int p = tmp[e];
        int pos = atomicAdd(&cnt[p & 255], 1);
        srcs[pos] = p >> 8;
    }
}

// ---- gcnt: parallel LDS histogram over sorted batch ids ----
__global__ __launch_bounds__(256) void gcnt_kernel(const int* __restrict__ batch,
                                                   float* __restrict__ gcnt) {
    __shared__ int h[GG];
    if (threadIdx.x < GG) h[threadIdx.x] = 0;
    __syncthreads();
    int n = blockIdx.x * 256 + threadIdx.x;
    if (n < NN) atomicAdd(&h[batch[n]], 1);
    __syncthreads();
    if (threadIdx.x < GG && h[threadIdx.x])
        atomicAdd(&gcnt[threadIdx.x], (float)h[threadIdx.x]);
}

// ---- cast x (fp32) -> hb (fp16); runs AFTER bsort (hb overlaps tmp) ----
__global__ __launch_bounds__(256) void cast_kernel(const float* __restrict__ x,
                                                   _Float16* __restrict__ hb) {
    int i = blockIdx.x * 256 + threadIdx.x;  // one float4 per thread
    if (i >= NN * 16) return;
    float4 v = ((const float4*)x)[i];
    f16x4 o = {(_Float16)v.x, (_Float16)v.y, (_Float16)v.z, (_Float16)v.w};
    ((f16x4*)hb)[i] = o;
}

// ---- swizzle W (fp32 row-major [k][n]) into MFMA B-frag order, hi/lo fp16 ----
__global__ __launch_bounds__(256) void wswz_kernel(const float* __restrict__ W0,
                                                   const float* __restrict__ W1,
                                                   const float* __restrict__ W2,
                                                   _Float16* __restrict__ Wh) {
    const float* Wl = (blockIdx.x == 0) ? W0 : (blockIdx.x == 1) ? W1 : W2;
    _Float16* out = Wh + blockIdx.x * 16384;
    for (int c = threadIdx.x; c < 512; c += 256) {  // t(4) x h(2) x lane(64)
        int t = c >> 7;
        int h = (c >> 6) & 1;
        int lane = c & 63;
        int quad = lane >> 4;
        int n = lane & 15;
#pragma unroll
        for (int j = 0; j < 8; j++) {
            int k = h * 32 + quad * 8 + j;
            float w = Wl[k * 64 + t * 16 + n];
            _Float16 hi = (_Float16)w;
            _Float16 lo = (_Float16)(w - (float)hi);
            out[(((t * 2 + h) * 2 + 0) * 64 + lane) * 8 + j] = hi;
            out[(((t * 2 + h) * 2 + 1) * 64 + lane) * 8 + j] = lo;
        }
    }
}

// ---- MFMA gemm: fp16 A rows -> fp32 u eighth-tables via LDS transpose ----
__global__ __launch_bounds__(256) void gemm_mfma_kernel(const _Float16* __restrict__ hin,
                                                        const _Float16* __restrict__ Whl,
                                                        const float* __restrict__ dinv,
                                                        float* __restrict__ u32) {
    __shared__ float lds[4][4][16][16];  // [wave][quarter][node][feat] = 16KB
    int wv = threadIdx.x >> 6;
    int wid = blockIdx.x * 4 + wv;
    int lane = threadIdx.x & 63;
    int m = lane & 15;
    int quad = lane >> 4;
    bool active = (wid < NN / 16);
    int n0 = wid * 16;
    if (active) {
        f16x8 a0 = *(const f16x8*)(hin + (size_t)(n0 + m) * 64 + quad * 8);
        f16x8 a1 = *(const f16x8*)(hin + (size_t)(n0 + m) * 64 + 32 + quad * 8);

        f32x4 acc[4];
#pragma unroll
        for (int t = 0; t < 4; t++) acc[t] = (f32x4){0.f, 0.f, 0.f, 0.f};
#pragma unroll
        for (int t = 0; t < 4; t++) {
            f16x8 bh0 = *(const f16x8*)(Whl + (((t * 2 + 0) * 2 + 0) * 64 + lane) * 8);
            f16x8 bl0 = *(const f16x8*)(Whl + (((t * 2 + 0) * 2 + 1) * 64 + lane) * 8);
            f16x8 bh1 = *(const f16x8*)(Whl + (((t * 2 + 1) * 2 + 0) * 64 + lane) * 8);
            f16x8 bl1 = *(const f16x8*)(Whl + (((t * 2 + 1) * 2 + 1) * 64 + lane) * 8);
            acc[t] = __builtin_amdgcn_mfma_f32_16x16x32_f16(a0, bh0, acc[t], 0, 0, 0);
            acc[t] = __builtin_amdgcn_mfma_f32_16x16x32_f16(a0, bl0, acc[t], 0, 0, 0);
            acc[t] = __builtin_amdgcn_mfma_f32_16x16x32_f16(a1, bh1, acc[t], 0, 0, 0);
            acc[t] = __builtin_amdgcn_mfma_f32_16x16x32_f16(a1, bl1, acc[t], 0, 0, 0);
        }
        // D layout: col = lane&15 (= feature in quarter), row = quad*4 + reg (= node)
        float4 dv4 = *(const float4*)(dinv + n0 + quad * 4);
        const float* dvp = (const float*)&dv4;
#pragma unroll
        for (int t = 0; t < 4; t++)
#pragma unroll
            for (int i = 0; i < 4; i++)
                lds[wv][t][quad * 4 + i][m] = acc[t][i] * dvp[i];
    }
    __syncthreads();
    if (active) {
        int node = lane & 15;
        int sel = lane >> 4;
        int half = sel & 1;    // which eighth of the quarter
        int chunk = sel >> 1;  // which float4 of the 8-float row
#pragma unroll
        for (int t = 0; t < 4; t++) {
            f32x4 v = *(const f32x4*)&lds[wv][t][node][half * 8 + chunk * 4];
            size_t e8 = (size_t)(t * 2 + half);
            *(f32x4*)(u32 + (e8 * NN + n0 + node) * 8 + chunk * 4) = v;
        }
    }
}

// ---- eighth gather: 2 lanes per edge-eighth, 16B fp32 loads (pk_add path) ----
// lane = ng*8 + sub*2 + fl : ng = node (8/wave), sub = edge slot (4), fl = half-row.
__device__ __forceinline__ void gather8(const float* __restrict__ uq,
                                        const int* __restrict__ srcs,
                                        int n, int sub, int fl, int rs, int len,
                                        f32x4& a) {
    a = (f32x4){0.f, 0.f, 0.f, 0.f};
    if (sub == 0) a = *(const f32x4*)(uq + (size_t)n * 8 + fl * 4);
    int e = rs + sub, end = rs + len;
    for (; e + 4 < end; e += 8) {
        int sA = srcs[e];
        int sB = srcs[e + 4];
        f32x4 ra = *(const f32x4*)(uq + (size_t)sA * 8 + fl * 4);
        f32x4 rb = *(const f32x4*)(uq + (size_t)sB * 8 + fl * 4);
        a += ra;
        a += rb;
    }
    if (e < end) a += *(const f32x4*)(uq + (size_t)srcs[e] * 8 + fl * 4);
}

__device__ __forceinline__ void sub_reduce4(f32x4& a) {
#pragma unroll
    for (int m = 2; m <= 4; m <<= 1) {
#pragma unroll
        for (int i = 0; i < 4; i++) a[i] += __shfl_xor(a[i], m);
    }
}

// layers 0,1: block = 32 nodes x 1 eighth; e8 = blockIdx&7 (one 3.2MB table/XCD)
__global__ __launch_bounds__(256) void agg_kernel(const float* __restrict__ u32,
                                                  const int* __restrict__ srcs,
                                                  const int* __restrict__ rowStart,
                                                  const int* __restrict__ rowLen,
                                                  const float* __restrict__ dinv,
                                                  const float* __restrict__ bias,
                                                  _Float16* __restrict__ hout) {
    int e8 = blockIdx.x & 7;
    int grp = blockIdx.x >> 3;
    int w = threadIdx.x >> 6;
    int lane = threadIdx.x & 63;
    int ng = lane >> 3;
    int sub = (lane >> 1) & 3;
    int fl = lane & 1;
    int n = grp * 32 + w * 8 + ng;
    const float* uq = u32 + (size_t)e8 * NN * 8;
    int rs = rowStart[n], len = rowLen[n];
    f32x4 a;
    gather8(uq, srcs, n, sub, fl, rs, len, a);
    sub_reduce4(a);
    if (sub == 0) {
        float dv = dinv[n];
        float4 bb = *(const float4*)(bias + e8 * 8 + fl * 4);
        f16x4 o;
        o[0] = (_Float16)fmaxf(fmaf(dv, a[0], bb.x), 0.0f);
        o[1] = (_Float16)fmaxf(fmaf(dv, a[1], bb.y), 0.0f);
        o[2] = (_Float16)fmaxf(fmaf(dv, a[2], bb.z), 0.0f);
        o[3] = (_Float16)fmaxf(fmaf(dv, a[3], bb.w), 0.0f);
        *(f16x4*)(hout + (size_t)n * 64 + e8 * 8 + fl * 4) = o;
    }
}

// layer 2 fused with mean-pool partial sums (32 nodes x 1 eighth per block)
__global__ __launch_bounds__(256) void agg_pool_kernel(const float* __restrict__ u32,
                                                       const int* __restrict__ srcs,
                                                       const int* __restrict__ rowStart,
                                                       const int* __restrict__ rowLen,
                                                       const float* __restrict__ dinv,
                                                       const float* __restrict__ bias,
                                                       const int* __restrict__ batch,
                                                       float* __restrict__ gsum) {
    int e8 = blockIdx.x & 7;
    int grp = blockIdx.x >> 3;
    int w = threadIdx.x >> 6;
    int lane = threadIdx.x & 63;
    int ng = lane >> 3;
    int sub = (lane >> 1) & 3;
    int fl = lane & 1;
    int n = grp * 32 + w * 8 + ng;
    const float* uq = u32 + (size_t)e8 * NN * 8;
    __shared__ float vals[32][8];
    __shared__ int gid[32];
    int rs = rowStart[n], len = rowLen[n];
    f32x4 a;
    gather8(uq, srcs, n, sub, fl, rs, len, a);
    sub_reduce4(a);
    if (sub == 0) {
        float dv = dinv[n];
        float4 bb = *(const float4*)(bias + e8 * 8 + fl * 4);
        float4 r;
        r.x = fmaxf(fmaf(dv, a[0], bb.x), 0.0f);
        r.y = fmaxf(fmaf(dv, a[1], bb.y), 0.0f);
        r.z = fmaxf(fmaf(dv, a[2], bb.z), 0.0f);
        r.w = fmaxf(fmaf(dv, a[3], bb.w), 0.0f);
        *(float4*)(&vals[w * 8 + ng][fl * 4]) = r;
    }
    if ((lane & 7) == 0) gid[w * 8 + ng] = batch[n];
    __syncthreads();
    if (threadIdx.x < 8) {
        int t = threadIdx.x;
        float run = vals[0][t];
        int curg = gid[0];
        for (int j = 1; j < 32; j++) {
            int gj = gid[j];
            if (gj != curg) {
                atomicAdd(&gsum[curg * 64 + e8 * 8 + t], run);
                curg = gj;
                run = 0.0f;
            }
            run += vals[j][t];
        }
        atomicAdd(&gsum[curg * 64 + e8 * 8 + t], run);
    }
}

__global__ __launch_bounds__(128) void final_kernel(const float* __restrict__ gsum,
                                                    const float* __restrict__ gcnt,
                                                    const float* __restrict__ Wlin,
                                                    const float* __restrict__ blin,
                                                    float* __restrict__ out) {
    int t = threadIdx.x;  // 128 = G*C
    int g = t >> 1;
    int c = t & 1;
    float cnt = fmaxf(gcnt[g], 1.0f);
    float s = 0.0f;
#pragma unroll
    for (int k = 0; k < 64; k++) s = fmaf(gsum[g * 64 + k], Wlin[k * 2 + c], s);
    out[t] = s / cnt + blin[c];
}

extern "C" void kernel_launch(void* const* d_in, const int* in_sizes, int n_in,
                              void* d_out, int out_size, void* d_ws, size_t ws_size,
                              hipStream_t stream) {
    const float* x     = (const float*)d_in[0];
    const int*   ei    = (const int*)d_in[1];
    const int*   batch = (const int*)d_in[2];
    const float* W0    = (const float*)d_in[3];
    const float* b0    = (const float*)d_in[4];
    const float* W1    = (const float*)d_in[5];
    const float* b1    = (const float*)d_in[6];
    const float* W2    = (const float*)d_in[7];
    const float* b2    = (const float*)d_in[8];
    const float* Wlin  = (const float*)d_in[9];
    const float* blin  = (const float*)d_in[10];
    float* out = (float*)d_out;

    char* ws = (char*)d_ws;
    int*      rowStart = (int*)(ws + 0);
    int*      rowLen   = (int*)(ws + 400000);
    float*    dinv     = (float*)(ws + 800000);
    int*      srcs     = (int*)(ws + 1200000);
    float*    u32      = (float*)(ws + 14012288);    // 8 x NN x 8 fp32, ends 39612288
    _Float16* hb       = (_Float16*)(ws + 39612288); // fp16 NN x 64, ends 52412288
    int*      tmp      = (int*)(ws + 39612288);      // overlaps hb; dead after bsort
    _Float16* Wh       = (_Float16*)(ws + 52424576); // 3 x 32768 B, ends 52522880
    float*    gsum     = (float*)(ws + 52522880);
    float*    gcnt     = (float*)(ws + 52539264);
    int*      bcur     = (int*)(ws + 52539520);

    // zero gsum+gcnt+bcur (contiguous)
    hipMemsetAsync(ws + 52522880, 0, 18204, stream);

    // CSR build first (tmp shares hb region; cast must follow bsort)
    bplace_kernel<<<cdiv_h(EE, 4096), 256, 0, stream>>>(ei, bcur, tmp);
    bsort_kernel<<<NBK, 256, 0, stream>>>(tmp, bcur, rowStart, rowLen, dinv, srcs);
    gcnt_kernel<<<NBK, 256, 0, stream>>>(batch, gcnt);
    cast_kernel<<<cdiv_h(NN * 16, 256), 256, 0, stream>>>(x, hb);
    wswz_kernel<<<3, 256, 0, stream>>>(W0, W1, W2, Wh);

    int gemm_blocks = cdiv_h(NN / 16, 4);    // 6250 waves, 16 rows, all quarters
    int agg_blocks = (NN / 32) * 8;          // 3125 node-groups x 8 feature eighths

    gemm_mfma_kernel<<<gemm_blocks, 256, 0, stream>>>(hb, Wh, dinv, u32);
    agg_kernel<<<agg_blocks, 256, 0, stream>>>(u32, srcs, rowStart, rowLen, dinv, b0, hb);
    gemm_mfma_kernel<<<gemm_blocks, 256, 0, stream>>>(hb, Wh + 16384, dinv, u32);
    agg_kernel<<<agg_blocks, 256, 0, stream>>>(u32, srcs, rowStart, rowLen, dinv, b1, hb);
    gemm_mfma_kernel<<<gemm_blocks, 256, 0, stream>>>(hb, Wh + 32768, dinv, u32);
    agg_pool_kernel<<<agg_blocks, 256, 0, stream>>>(u32, srcs, rowStart, rowLen, dinv, b2, batch, gsum);

    final_kernel<<<1, 128, 0, stream>>>(gsum, gcnt, Wlin, blin, out);
}

// Round 18
// 307.640 us; speedup vs baseline: 1.3655x; 1.3655x over previous
//
#include <hip/hip_runtime.h>
#include <hip/hip_fp16.h>

#define NN 100000
#define EE 1600000
#define HH 64
#define GG 64
#define NBK 391    // buckets of 256 nodes: dst>>8
#define CAP 8192   // fixed bucket capacity (mean load 4092, max ~4400)

typedef _Float16 f16x8 __attribute__((ext_vector_type(8)));
typedef _Float16 f16x4 __attribute__((ext_vector_type(4)));
typedef float f32x4 __attribute__((ext_vector_type(4)));

// ---------------- workspace layout (bytes) ----------------
// rowStart : int[NN]          @ 0
// rowLen   : int[NN]          @ 400000
// dinv     : float[NN]        @ 800000
// srcs     : int[NBK*CAP]     @ 1200000   (ends 14012288)
// u        : half[4][NN][16]  @ 14012288  (ends 26812288)
// hb(half) : half[NN*64]      @ 26812288  (ends 39612288)
// tmp      : int[NBK*CAP]     @ 26812288  (overlaps hb; dead after bsort; agg0 then writes hb)
// Wh       : half[3][16384]   @ 52424576  (32KB/layer, ends 52522880)
// gsum     : float[4096]      @ 52522880
// gcnt     : float[64]        @ 52539264
// bcur     : int[NBK]         @ 52539520
//
// Failed-experiment ledger (keep!):
//  R8  col-split gemm: VALUBusy 6.8%, 2x slower (halved ILP per row-read)
//  R13 producer-local gemm: agg FETCH unchanged (L2 invalidated at dispatch edge)
//  R15 warm_slice + nt hints: agg 46->69us, FETCH 31->41MB (nt evicts srcs)
//  R17 fp32 eighth-tables: VALU 43->29% but bytes/edge 2x -> agg 46->83us
//  => R16 fp16-quarter gather (46us, 31MB) is the converged agg structure.

static inline int cdiv_h(int a, int b) { return (a + b - 1) / b; }

// ---- partition edges into fixed-capacity buckets (391 blocks x 4096 edges) ----
__global__ __launch_bounds__(256) void bplace_kernel(const int* __restrict__ ei,
                                                     int* __restrict__ bcur,
                                                     int* __restrict__ tmp) {
    __shared__ int h[NBK];
    __shared__ int boff[NBK];
    for (int t = threadIdx.x; t < NBK; t += 256) h[t] = 0;
    __syncthreads();
    int base = blockIdx.x * 4096;
#pragma unroll 4
    for (int i = 0; i < 16; i++) {
        int e = base + i * 256 + threadIdx.x;
        if (e < EE) atomicAdd(&h[ei[EE + e] >> 8], 1);
    }
    __syncthreads();
    for (int t = threadIdx.x; t < NBK; t += 256) {
        int c = h[t];
        boff[t] = c ? (t * CAP + atomicAdd(&bcur[t], c)) : 0;
        h[t] = 0;  // reuse as running cursor
    }
    __syncthreads();
#pragma unroll 4
    for (int i = 0; i < 16; i++) {
        int e = base + i * 256 + threadIdx.x;
        if (e < EE) {
            int s0 = ei[e];
            int d = ei[EE + e];
            int b = d >> 8;
            int p = boff[b] + atomicAdd(&h[b], 1);
            tmp[p] = (s0 << 8) | (d & 255);
        }
    }
}

// ---- per-bucket counting sort: srcs (bucket-strided CSR), rowStart/Len, dinv ----
__global__ __launch_bounds__(256) void bsort_kernel(const int* __restrict__ tmp,
                                                    const int* __restrict__ bcur,
                                                    int* __restrict__ rowStart,
                                                    int* __restrict__ rowLen,
                                                    float* __restrict__ dinv,
                                                    int* __restrict__ srcs) {
    int b = blockIdx.x;
    int n0 = b << 8;
    int e0 = b * CAP;
    int e1 = e0 + bcur[b];
    int t = threadIdx.x;
    __shared__ int cnt[256];
    __shared__ int st[256];
    cnt[t] = 0;
    __syncthreads();
    for (int e = e0 + t; e < e1; e += 256) atomicAdd(&cnt[tmp[e] & 255], 1);
    __syncthreads();
    int v = cnt[t];
    st[t] = v;
    __syncthreads();
    for (int off = 1; off < 256; off <<= 1) {
        int w = (t >= off) ? st[t - off] : 0;
        __syncthreads();
        st[t] += w;
        __syncthreads();
    }
    int excl = st[t] - v;
    int n = n0 + t;
    if (n < NN) {
        rowStart[n] = e0 + excl;
        rowLen[n] = v;
        dinv[n] = rsqrtf((float)v + 1.0f);
    }
    __syncthreads();
    cnt[t] = e0 + excl;  // absolute cursor
    __syncthreads();
    for (int e = e0 + t; e < e1; e += 256) {
        int p = tmp[e];
        int pos = atomicAdd(&cnt[p & 255], 1);
        srcs[pos] = p >> 8;
    }
}

// ---- merged prep: blocks 0-2 = W swizzle (hi/lo B-frags); blocks 3+ = gcnt ----
__global__ __launch_bounds__(256) void prep_kernel(const float* __restrict__ W0,
                                                   const float* __restrict__ W1,
                                                   const float* __restrict__ W2,
                                                   _Float16* __restrict__ Wh,
                                                   const int* __restrict__ batch,
                                                   float* __restrict__ gcnt) {
    if (blockIdx.x < 3) {
        const float* Wl = (blockIdx.x == 0) ? W0 : (blockIdx.x == 1) ? W1 : W2;
        _Float16* out = Wh + blockIdx.x * 16384;
        for (int c = threadIdx.x; c < 512; c += 256) {  // t(4) x h(2) x lane(64)
            int t = c >> 7;
            int h = (c >> 6) & 1;
            int lane = c & 63;
            int quad = lane >> 4;
            int n = lane & 15;
#pragma unroll
            for (int j = 0; j < 8; j++) {
                int k = h * 32 + quad * 8 + j;
                float w = Wl[k * 64 + t * 16 + n];
                _Float16 hi = (_Float16)w;
                _Float16 lo = (_Float16)(w - (float)hi);
                out[(((t * 2 + h) * 2 + 0) * 64 + lane) * 8 + j] = hi;
                out[(((t * 2 + h) * 2 + 1) * 64 + lane) * 8 + j] = lo;
            }
        }
    } else {
        __shared__ int h[GG];
        if (threadIdx.x < GG) h[threadIdx.x] = 0;
        __syncthreads();
        int n = (blockIdx.x - 3) * 256 + threadIdx.x;
        if (n < NN) atomicAdd(&h[batch[n]], 1);
        __syncthreads();
        if (threadIdx.x < GG && h[threadIdx.x])
            atomicAdd(&gcnt[threadIdx.x], (float)h[threadIdx.x]);
    }
}

// ---- MFMA gemm core (A frags in registers -> u quarter tables via LDS) ----
__device__ __forceinline__ void gemm_core(f16x8 a0, f16x8 a1,
                                          const _Float16* __restrict__ Whl,
                                          const float* __restrict__ dinv,
                                          _Float16* __restrict__ u,
                                          int wv, int lane, int n0, bool active,
                                          _Float16 (*lds)[4][16][16]) {
    int m = lane & 15;
    int quad = lane >> 4;
    if (active) {
        f32x4 acc[4];
#pragma unroll
        for (int t = 0; t < 4; t++) acc[t] = (f32x4){0.f, 0.f, 0.f, 0.f};
#pragma unroll
        for (int t = 0; t < 4; t++) {
            f16x8 bh0 = *(const f16x8*)(Whl + (((t * 2 + 0) * 2 + 0) * 64 + lane) * 8);
            f16x8 bl0 = *(const f16x8*)(Whl + (((t * 2 + 0) * 2 + 1) * 64 + lane) * 8);
            f16x8 bh1 = *(const f16x8*)(Whl + (((t * 2 + 1) * 2 + 0) * 64 + lane) * 8);
            f16x8 bl1 = *(const f16x8*)(Whl + (((t * 2 + 1) * 2 + 1) * 64 + lane) * 8);
            acc[t] = __builtin_amdgcn_mfma_f32_16x16x32_f16(a0, bh0, acc[t], 0, 0, 0);
            acc[t] = __builtin_amdgcn_mfma_f32_16x16x32_f16(a0, bl0, acc[t], 0, 0, 0);
            acc[t] = __builtin_amdgcn_mfma_f32_16x16x32_f16(a1, bh1, acc[t], 0, 0, 0);
            acc[t] = __builtin_amdgcn_mfma_f32_16x16x32_f16(a1, bl1, acc[t], 0, 0, 0);
        }
        // D layout: col = lane&15 (= feature), row = quad*4 + reg (= node) [m89/m91]
        float4 dv4 = *(const float4*)(dinv + n0 + quad * 4);
        const float* dvp = (const float*)&dv4;
#pragma unroll
        for (int t = 0; t < 4; t++)
#pragma unroll
            for (int i = 0; i < 4; i++)
                lds[wv][t][quad * 4 + i][m] = (_Float16)(acc[t][i] * dvp[i]);
    }
    __syncthreads();
    if (active) {
        int t = lane >> 4;
        int node = lane & 15;
        f16x8 v0 = *(const f16x8*)&lds[wv][t][node][0];
        f16x8 v1 = *(const f16x8*)&lds[wv][t][node][8];
        _Float16* dst = u + ((size_t)t * NN + n0 + node) * 16;
        *(f16x8*)dst = v0;
        *(f16x8*)(dst + 8) = v1;
    }
}

// layer 0: fp32 x rows, convert to A-frags in-register (no cast pass needed)
__global__ __launch_bounds__(256) void gemm_mfma_f32_kernel(const float* __restrict__ hin,
                                                            const _Float16* __restrict__ Whl,
                                                            const float* __restrict__ dinv,
                                                            _Float16* __restrict__ u) {
    __shared__ _Float16 lds[4][4][16][16];  // 8KB
    int wv = threadIdx.x >> 6;
    int wid = blockIdx.x * 4 + wv;
    int lane = threadIdx.x & 63;
    int m = lane & 15;
    int quad = lane >> 4;
    bool active = (wid < NN / 16);
    int n0 = wid * 16;
    f16x8 a0 = {}, a1 = {};
    if (active) {
        const float* row = hin + (size_t)(n0 + m) * 64 + quad * 8;
        float4 p0 = *(const float4*)(row);
        float4 p1 = *(const float4*)(row + 4);
        float4 p2 = *(const float4*)(row + 32);
        float4 p3 = *(const float4*)(row + 36);
        a0[0] = (_Float16)p0.x; a0[1] = (_Float16)p0.y; a0[2] = (_Float16)p0.z; a0[3] = (_Float16)p0.w;
        a0[4] = (_Float16)p1.x; a0[5] = (_Float16)p1.y; a0[6] = (_Float16)p1.z; a0[7] = (_Float16)p1.w;
        a1[0] = (_Float16)p2.x; a1[1] = (_Float16)p2.y; a1[2] = (_Float16)p2.z; a1[3] = (_Float16)p2.w;
        a1[4] = (_Float16)p3.x; a1[5] = (_Float16)p3.y; a1[6] = (_Float16)p3.z; a1[7] = (_Float16)p3.w;
    }
    gemm_core(a0, a1, Whl, dinv, u, wv, lane, n0, active, lds);
}

// layers 1,2: fp16 hb rows
__global__ __launch_bounds__(256) void gemm_mfma_kernel(const _Float16* __restrict__ hin,
                                                        const _Float16* __restrict__ Whl,
                                                        const float* __restrict__ dinv,
                                                        _Float16* __restrict__ u) {
    __shared__ _Float16 lds[4][4][16][16];  // 8KB
    int wv = threadIdx.x >> 6;
    int wid = blockIdx.x * 4 + wv;
    int lane = threadIdx.x & 63;
    int m = lane & 15;
    int quad = lane >> 4;
    bool active = (wid < NN / 16);
    int n0 = wid * 16;
    f16x8 a0 = {}, a1 = {};
    if (active) {
        a0 = *(const f16x8*)(hin + (size_t)(n0 + m) * 64 + quad * 8);
        a1 = *(const f16x8*)(hin + (size_t)(n0 + m) * 64 + 32 + quad * 8);
    }
    gemm_core(a0, a1, Whl, dinv, u, wv, lane, n0, active, lds);
}

// ---- quarter gather: 2 lanes per edge-quarter, 16B loads, 8 nodes per wave ----
__device__ __forceinline__ void add8(float4 raw, float* a) {
    const __half2* h = (const __half2*)&raw;
#pragma unroll
    for (int i = 0; i < 4; i++) {
        float2 f = __half22float2(h[i]);
        a[2 * i] += f.x;
        a[2 * i + 1] += f.y;
    }
}

__device__ __forceinline__ void gatherq8(const __half* __restrict__ uq,
                                         const int* __restrict__ srcs,
                                         int n, int sub, int fl, int rs, int len,
                                         float* a) {
#pragma unroll
    for (int i = 0; i < 8; i++) a[i] = 0.0f;
    if (sub == 0)
        add8(*(const float4*)(uq + (size_t)n * 16 + fl * 8), a);
    int e = rs + sub, end = rs + len;
    for (; e + 4 < end; e += 8) {
        int sA = srcs[e];
        int sB = srcs[e + 4];
        float4 ra = *(const float4*)(uq + (size_t)sA * 16 + fl * 8);
        float4 rb = *(const float4*)(uq + (size_t)sB * 16 + fl * 8);
        add8(ra, a);
        add8(rb, a);
    }
    if (e < end)
        add8(*(const float4*)(uq + (size_t)srcs[e] * 16 + fl * 8), a);
}

__device__ __forceinline__ void sub_reduce8(float* a) {
#pragma unroll
    for (int m = 2; m <= 4; m <<= 1) {
#pragma unroll
        for (int i = 0; i < 8; i++) a[i] += __shfl_xor(a[i], m);
    }
}

__device__ __forceinline__ void relu_bias8(const float* a, float dv,
                                           const float* bias_p, float* r) {
    const float4* bb = (const float4*)bias_p;
    float4 b0 = bb[0], b1 = bb[1];
    r[0] = fmaxf(fmaf(dv, a[0], b0.x), 0.0f);
    r[1] = fmaxf(fmaf(dv, a[1], b0.y), 0.0f);
    r[2] = fmaxf(fmaf(dv, a[2], b0.z), 0.0f);
    r[3] = fmaxf(fmaf(dv, a[3], b0.w), 0.0f);
    r[4] = fmaxf(fmaf(dv, a[4], b1.x), 0.0f);
    r[5] = fmaxf(fmaf(dv, a[5], b1.y), 0.0f);
    r[6] = fmaxf(fmaf(dv, a[6], b1.z), 0.0f);
    r[7] = fmaxf(fmaf(dv, a[7], b1.w), 0.0f);
}

// layers 0,1: block = 32 nodes x 1 quarter; q = blockIdx&3. fp16 out.
__global__ __launch_bounds__(256) void agg_kernel(const __half* __restrict__ u,
                                                  const int* __restrict__ srcs,
                                                  const int* __restrict__ rowStart,
                                                  const int* __restrict__ rowLen,
                                                  const float* __restrict__ dinv,
                                                  const float* __restrict__ bias,
                                                  __half* __restrict__ hout) {
    int q = blockIdx.x & 3;
    int grp = blockIdx.x >> 2;
    int w = threadIdx.x >> 6;
    int lane = threadIdx.x & 63;
    int ng = lane >> 3;
    int sub = (lane >> 1) & 3;
    int fl = lane & 1;
    int n = grp * 32 + w * 8 + ng;
    const __half* uq = u + (size_t)q * NN * 16;
    int rs = rowStart[n], len = rowLen[n];
    float a[8];
    gatherq8(uq, srcs, n, sub, fl, rs, len, a);
    sub_reduce8(a);
    if (sub == 0) {
        float r[8];
        relu_bias8(a, dinv[n], bias + q * 16 + fl * 8, r);
        __half2 hh[4];
#pragma unroll
        for (int i = 0; i < 4; i++) hh[i] = __floats2half2_rn(r[2 * i], r[2 * i + 1]);
        *(float4*)(hout + (size_t)n * 64 + q * 16 + fl * 8) = *(float4*)hh;
    }
}

// layer 2 fused with mean-pool partial sums (32 nodes x 1 quarter per block)
__global__ __launch_bounds__(256) void agg_pool_kernel(const __half* __restrict__ u,
                                                       const int* __restrict__ srcs,
                                                       const int* __restrict__ rowStart,
                                                       const int* __restrict__ rowLen,
                                                       const float* __restrict__ dinv,
                                                       const float* __restrict__ bias,
                                                       const int* __restrict__ batch,
                                                       float* __restrict__ gsum) {
    int q = blockIdx.x & 3;
    int grp = blockIdx.x >> 2;
    int w = threadIdx.x >> 6;
    int lane = threadIdx.x & 63;
    int ng = lane >> 3;
    int sub = (lane >> 1) & 3;
    int fl = lane & 1;
    int n = grp * 32 + w * 8 + ng;
    const __half* uq = u + (size_t)q * NN * 16;
    __shared__ float vals[32][16];
    __shared__ int gid[32];
    int rs = rowStart[n], len = rowLen[n];
    float a[8];
    gatherq8(uq, srcs, n, sub, fl, rs, len, a);
    sub_reduce8(a);
    if (sub == 0) {
        float r[8];
        relu_bias8(a, dinv[n], bias + q * 16 + fl * 8, r);
        float4* vp = (float4*)(&vals[w * 8 + ng][fl * 8]);
        vp[0] = make_float4(r[0], r[1], r[2], r[3]);
        vp[1] = make_float4(r[4], r[5], r[6], r[7]);
    }
    if ((lane & 7) == 0) gid[w * 8 + ng] = batch[n];
    __syncthreads();
    if (threadIdx.x < 16) {
        int t = threadIdx.x;
        float run = vals[0][t];
        int curg = gid[0];
        for (int j = 1; j < 32; j++) {
            int gj = gid[j];
            if (gj != curg) {
                atomicAdd(&gsum[curg * 64 + q * 16 + t], run);
                curg = gj;
                run = 0.0f;
            }
            run += vals[j][t];
        }
        atomicAdd(&gsum[curg * 64 + q * 16 + t], run);
    }
}

__global__ __launch_bounds__(128) void final_kernel(const float* __restrict__ gsum,
                                                    const float* __restrict__ gcnt,
                                                    const float* __restrict__ Wlin,
                                                    const float* __restrict__ blin,
                                                    float* __restrict__ out) {
    int t = threadIdx.x;  // 128 = G*C
    int g = t >> 1;
    int c = t & 1;
    float cnt = fmaxf(gcnt[g], 1.0f);
    float s = 0.0f;
#pragma unroll
    for (int k = 0; k < 64; k++) s = fmaf(gsum[g * 64 + k], Wlin[k * 2 + c], s);
    out[t] = s / cnt + blin[c];
}

extern "C" void kernel_launch(void* const* d_in, const int* in_sizes, int n_in,
                              void* d_out, int out_size, void* d_ws, size_t ws_size,
                              hipStream_t stream) {
    const float* x     = (const float*)d_in[0];
    const int*   ei    = (const int*)d_in[1];
    const int*   batch = (const int*)d_in[2];
    const float* W0    = (const float*)d_in[3];
    const float* b0    = (const float*)d_in[4];
    const float* W1    = (const float*)d_in[5];
    const float* b1    = (const float*)d_in[6];
    const float* W2    = (const float*)d_in[7];
    const float* b2    = (const float*)d_in[8];
    const float* Wlin  = (const float*)d_in[9];
    const float* blin  = (const float*)d_in[10];
    float* out = (float*)d_out;

    char* ws = (char*)d_ws;
    int*      rowStart = (int*)(ws + 0);
    int*      rowLen   = (int*)(ws + 400000);
    float*    dinv     = (float*)(ws + 800000);
    int*      srcs     = (int*)(ws + 1200000);
    __half*   u        = (__half*)(ws + 14012288);
    __half*   hb       = (__half*)(ws + 26812288);
    int*      tmp      = (int*)(ws + 26812288);   // overlaps hb; dead after bsort
    _Float16* Wh       = (_Float16*)(ws + 52424576);  // 3 x 32768 B, ends 52522880
    float*    gsum     = (float*)(ws + 52522880);
    float*    gcnt     = (float*)(ws + 52539264);
    int*      bcur     = (int*)(ws + 52539520);

    // zero gsum+gcnt+bcur (contiguous)
    hipMemsetAsync(ws + 52522880, 0, 18204, stream);

    // CSR build, then merged prep (W swizzle + gcnt)
    bplace_kernel<<<cdiv_h(EE, 4096), 256, 0, stream>>>(ei, bcur, tmp);
    bsort_kernel<<<NBK, 256, 0, stream>>>(tmp, bcur, rowStart, rowLen, dinv, srcs);
    prep_kernel<<<3 + cdiv_h(NN, 256), 256, 0, stream>>>(W0, W1, W2, Wh, batch, gcnt);

    int gemm_blocks = cdiv_h(NN / 16, 4);    // 6250 waves, 16 rows, all quarters
    int agg_blocks = (NN / 32) * 4;          // 3125 node-groups x 4 quarters

    gemm_mfma_f32_kernel<<<gemm_blocks, 256, 0, stream>>>(x, Wh, dinv, (_Float16*)u);
    agg_kernel<<<agg_blocks, 256, 0, stream>>>(u, srcs, rowStart, rowLen, dinv, b0, hb);
    gemm_mfma_kernel<<<gemm_blocks, 256, 0, stream>>>((const _Float16*)hb, Wh + 16384, dinv, (_Float16*)u);
    agg_kernel<<<agg_blocks, 256, 0, stream>>>(u, srcs, rowStart, rowLen, dinv, b1, hb);
    gemm_mfma_kernel<<<gemm_blocks, 256, 0, stream>>>((const _Float16*)hb, Wh + 32768, dinv, (_Float16*)u);
    agg_pool_kernel<<<agg_blocks, 256, 0, stream>>>(u, srcs, rowStart, rowLen, dinv, b2, batch, gsum);

    final_kernel<<<1, 128, 0, stream>>>(gsum, gcnt, Wlin, blin, out);
}